// Round 16
// baseline (412.770 us; speedup 1.0000x reference)
//
#include <hip/hip_runtime.h>

#define RES 256
#define NV 6890
#define NXY (32*32)                     // 2-D xy cells (8x8 voxels each)
#define XCAP 64                         // per xy-cell capacity (mean ~10, Poisson tail ~1e-30)
#define SEM_ELEMS (RES*RES*RES*3)
#define OUT_QUADS ((SEM_ELEMS + RES*RES*RES) / 4)   // 16,777,216 f32x4
#define SEM_QUADS (SEM_ELEMS / 4)                   // 12,582,912 f32x4
#define INIT_THREADS (2048 * 256)                   // 524,288 -> 32 stores/thread

typedef float f32x4 __attribute__((ext_vector_type(4)));

// ---------------------------------------------------------------------------
// Kernel 1: default-fill the output (sem=0, wsum=0.001), fill-shaped in BOTH
// access pattern and loop structure: 2048 blocks, grid-stride, 32 plain f32x4
// stores per thread (1 KB contiguous per wave-instruction), amortizing wave
// launch/setup like __amd_rocclr_fillBufferAligned does. First 1024 threads
// also zero the xy-cell counters.
// ---------------------------------------------------------------------------
__global__ void svox_init(f32x4* __restrict__ out, int* __restrict__ counts) {
    int i = blockIdx.x * blockDim.x + threadIdx.x;
    if (i < NXY) counts[i] = 0;
    const f32x4 z = {0.f, 0.f, 0.f, 0.f};
    const f32x4 w = {0.001f, 0.001f, 0.001f, 0.001f};
#pragma unroll 4
    for (int k = i; k < OUT_QUADS; k += INIT_THREADS)
        out[k] = (k < SEM_QUADS) ? z : w;
}

// ---------------------------------------------------------------------------
// Kernel 2: bucket vertices by (cx>>3, cy>>3). Packed record:
//   rec0 = (vx, vy, vz, bitcast((cx+8)<<20 | (cy+8)<<10 | (cz+8)))
//   rec1 = (c0, c1, c2, 0)
// Biased centers clamped to [0,1023] can never pass |voxel-center|<=3, so
// edge clamping is value-exact.
// ---------------------------------------------------------------------------
__global__ void svox_bucket_xy(const float* __restrict__ verts,
                               const float* __restrict__ codes,
                               int* __restrict__ counts,
                               f32x4* __restrict__ lists) {
    int n = blockIdx.x * blockDim.x + threadIdx.x;
    if (n >= NV) return;
    float vx = verts[3 * n + 0], vy = verts[3 * n + 1], vz = verts[3 * n + 2];
    int cx = (int)floorf((vx + 0.5f) * 256.0f);
    int cy = (int)floorf((vy + 0.5f) * 256.0f);
    int cz = (int)floorf((vz + 0.5f) * 256.0f);
    int px = min(max(cx + 8, 0), 1023);
    int py = min(max(cy + 8, 0), 1023);
    int pz = min(max(cz + 8, 0), 1023);
    int bx = min(max(cx >> 3, 0), 31);
    int by = min(max(cy >> 3, 0), 31);
    int cell = (bx << 5) | by;
    int slot = atomicAdd(&counts[cell], 1);
    if (slot < XCAP) {
        int pk = (px << 20) | (py << 10) | pz;
        f32x4 r0 = {vx, vy, vz, __int_as_float(pk)};
        f32x4 r1 = {codes[3 * n + 0], codes[3 * n + 1], codes[3 * n + 2], 0.0f};
        lists[(cell * XCAP + slot) * 2 + 0] = r0;
        lists[(cell * XCAP + slot) * 2 + 1] = r1;
    }
}

// ---------------------------------------------------------------------------
// Kernel 3: sparse gather. One WAVE per (x,y) column; lane owns a z-quad.
// Candidates (<=4 xy-cells, wave-uniform list) scanned with scalar rejection
// on the uniform xy window; z work per-lane predicated. A lane stores only if
// it accumulated any weight (aw>0 <=> differs from the init default; accepted
// w >= e^-4.6 so detection is exact). Untouched quads within an active lane
// store 0 / 0.001 == init values. Plain stores (L2-combined).
// ---------------------------------------------------------------------------
__global__ void __launch_bounds__(256)
svox_gather(const float* __restrict__ occ,
            const int* __restrict__ counts,
            const f32x4* __restrict__ lists,
            f32x4* __restrict__ sem4,
            f32x4* __restrict__ wsum4) {
    int lane = threadIdx.x & 63;
    int wid  = threadIdx.x >> 6;
    int col  = __builtin_amdgcn_readfirstlane((int)(blockIdx.x * 4 + wid));
    int x = col >> 8, y = col & 255;
    int z0 = lane << 2;

    // candidate cells for xy window +-3
    int cx0 = max(x - 3, 0) >> 3, cx1 = min(x + 3, 255) >> 3;
    int cy0 = max(y - 3, 0) >> 3, cy1 = min(y + 3, 255) >> 3;

    int tot = 0;
    for (int cx = cx0; cx <= cx1; ++cx)
        for (int cy = cy0; cy <= cy1; ++cy)
            tot += counts[(cx << 5) | cy];
    if (tot == 0) return;                         // init already wrote defaults

    float acc[4][4];
#pragma unroll
    for (int q = 0; q < 4; ++q) {
        acc[q][0] = 0.f; acc[q][1] = 0.f; acc[q][2] = 0.f; acc[q][3] = 0.f;
    }

    const float inv = 1.0f / 256.0f;
    float fx  = ((float)x  + 0.5f) * inv - 0.5f;
    float fy  = ((float)y  + 0.5f) * inv - 0.5f;
    float fz0 = ((float)z0 + 0.5f) * inv - 0.5f;

    int lin0 = (col << 8) + z0;
    const f32x4 o4 = __builtin_nontemporal_load((const f32x4*)&occ[lin0]);
    float occv[4] = {o4.x, o4.y, o4.z, o4.w};

    for (int cx = cx0; cx <= cx1; ++cx)
    for (int cy = cy0; cy <= cy1; ++cy) {
        int cell = (cx << 5) | cy;
        int cn = min(counts[cell], XCAP);
        int base = cell * XCAP * 2;
        for (int j = 0; j < cn; ++j) {
            f32x4 r0 = lists[base + 2 * j];       // wave-uniform address
            int pk = __float_as_int(r0.w);
            int cxb = (pk >> 20) & 1023;          // cx + 8
            int cyb = (pk >> 10) & 1023;
            int czb =  pk        & 1023;
            // wave-uniform xy window test -> scalar branch
            if ((unsigned)(x + 11 - cxb) > 6u || (unsigned)(y + 11 - cyb) > 6u)
                continue;
            f32x4 r1 = lists[base + 2 * j + 1];
            float dx = fx - r0.x, dy = fy - r0.y;
            float exy = __expf(-8192.0f * (dx * dx + dy * dy));
            // per-lane z-quad overlap: z0 - cz + 6 in [0,9]
            if ((unsigned)(z0 + 14 - czb) <= 9u) {
#pragma unroll
                for (int q = 0; q < 4; ++q) {
                    unsigned dzi = (unsigned)(z0 + q + 11 - czb);  // z - cz + 3
                    if (dzi > 6u) continue;
                    if (occv[q] <= 0.0f) continue;
                    float dz = fz0 + (float)q * inv - r0.z;
                    float w = exy * __expf(-8192.0f * dz * dz);
                    acc[q][0] += w * r1.x;
                    acc[q][1] += w * r1.y;
                    acc[q][2] += w * r1.z;
                    acc[q][3] += w;
                }
            }
        }
    }

    float aw = acc[0][3] + acc[1][3] + acc[2][3] + acc[3][3];
    if (aw > 0.0f) {                              // lane touched: 64B update
        int t = lin0 >> 2;                        // col*64 + lane
        f32x4 s0 = {acc[0][0], acc[0][1], acc[0][2], acc[1][0]};
        f32x4 s1 = {acc[1][1], acc[1][2], acc[2][0], acc[2][1]};
        f32x4 s2 = {acc[2][2], acc[3][0], acc[3][1], acc[3][2]};
        f32x4 sw = {0.001f + acc[0][3], 0.001f + acc[1][3],
                    0.001f + acc[2][3], 0.001f + acc[3][3]};
        sem4[t * 3 + 0] = s0;
        sem4[t * 3 + 1] = s1;
        sem4[t * 3 + 2] = s2;
        wsum4[t] = sw;
    }
}

extern "C" void kernel_launch(void* const* d_in, const int* in_sizes, int n_in,
                              void* d_out, int out_size, void* d_ws, size_t ws_size,
                              hipStream_t stream) {
    const float* verts = (const float*)d_in[0];   // (6890,3) f32
    const float* codes = (const float*)d_in[1];   // (6890,3) f32
    const float* occ   = (const float*)d_in[2];   // (256,256,256) f32
    // d_in[3] = smpl_faces (unused by the reference computation)

    f32x4* out4  = (f32x4*)d_out;
    f32x4* sem4  = (f32x4*)d_out;                       // 12,582,912 f32x4
    f32x4* wsum4 = (f32x4*)((float*)d_out + SEM_ELEMS); // 4,194,304 f32x4

    int*   counts = (int*)d_ws;                   // 4 KB
    f32x4* lists  = (f32x4*)(counts + 1024);      // 1024*64*2 f32x4 = 2 MB

    svox_init<<<2048, 256, 0, stream>>>(out4, counts);
    svox_bucket_xy<<<(NV + 255) / 256, 256, 0, stream>>>(verts, codes, counts, lists);
    svox_gather<<<(RES * RES) / 4, 256, 0, stream>>>(occ, counts, lists, sem4, wsum4);
}

// Round 17
// 366.529 us; speedup vs baseline: 1.1262x; 1.1262x over previous
//
#include <hip/hip_runtime.h>

#define RES 256
#define NV 6890
#define NXY (32*32)                     // 2-D xy cells (8x8 voxels each)
#define XCAP 64                         // per xy-cell capacity (mean ~10, Poisson tail ~1e-30)
#define SEM_ELEMS (RES*RES*RES*3)

typedef float f32x4 __attribute__((ext_vector_type(4)));

// ---------------------------------------------------------------------------
// Kernel 1: zero the xy-cell counters (d_ws is re-poisoned before every call).
// ---------------------------------------------------------------------------
__global__ void svox_zero(int* __restrict__ counts) {
    int i = blockIdx.x * blockDim.x + threadIdx.x;
    if (i < NXY) counts[i] = 0;
}

// ---------------------------------------------------------------------------
// Kernel 2: bucket vertices by (cx>>3, cy>>3). Packed record:
//   rec0 = (vx, vy, vz, bitcast((cx+8)<<20 | (cy+8)<<10 | (cz+8)))
//   rec1 = (c0, c1, c2, 0)
// Biased centers clamped to [0,1023] can never pass |voxel-center|<=3, so
// edge clamping is value-exact.
// ---------------------------------------------------------------------------
__global__ void svox_bucket_xy(const float* __restrict__ verts,
                               const float* __restrict__ codes,
                               int* __restrict__ counts,
                               f32x4* __restrict__ lists) {
    int n = blockIdx.x * blockDim.x + threadIdx.x;
    if (n >= NV) return;
    float vx = verts[3 * n + 0], vy = verts[3 * n + 1], vz = verts[3 * n + 2];
    int cx = (int)floorf((vx + 0.5f) * 256.0f);
    int cy = (int)floorf((vy + 0.5f) * 256.0f);
    int cz = (int)floorf((vz + 0.5f) * 256.0f);
    int px = min(max(cx + 8, 0), 1023);
    int py = min(max(cy + 8, 0), 1023);
    int pz = min(max(cz + 8, 0), 1023);
    int bx = min(max(cx >> 3, 0), 31);
    int by = min(max(cy >> 3, 0), 31);
    int cell = (bx << 5) | by;
    int slot = atomicAdd(&counts[cell], 1);
    if (slot < XCAP) {
        int pk = (px << 20) | (py << 10) | pz;
        f32x4 r0 = {vx, vy, vz, __int_as_float(pk)};
        f32x4 r1 = {codes[3 * n + 0], codes[3 * n + 1], codes[3 * n + 2], 0.0f};
        lists[(cell * XCAP + slot) * 2 + 0] = r0;
        lists[(cell * XCAP + slot) * 2 + 1] = r1;
    }
}

// ---------------------------------------------------------------------------
// Kernel 3: gather, defaults-first. One WAVE per (x,y) column; lane owns a
// z-quad. Every column ISSUES its 4 KB of default output (sem=0, wsum=0.001,
// fully contiguous per-wave stores) BEFORE the candidate scan, so the 268 MB
// write stream saturates DRAM from the start and compute overlaps the drain.
// After the scan, only lanes that accumulated weight (aw>0, exact since
// accepted w >= e^-4.6) re-store their 64 B; per-thread program order makes
// the rewrite land after the default, and L2 merges (line written once).
// ---------------------------------------------------------------------------
__global__ void __launch_bounds__(256)
svox_gather(const float* __restrict__ occ,
            const int* __restrict__ counts,
            const f32x4* __restrict__ lists,
            f32x4* __restrict__ sem4,
            f32x4* __restrict__ wsum4) {
    int lane = threadIdx.x & 63;
    int wid  = threadIdx.x >> 6;
    int col  = __builtin_amdgcn_readfirstlane((int)(blockIdx.x * 4 + wid));
    int x = col >> 8, y = col & 255;
    int z0 = lane << 2;

    int smbase = col * 192;                       // sem4 f32x4 base of column
    int wsbase = col << 6;                        // wsum4 base of column

    const f32x4 zq  = {0.f, 0.f, 0.f, 0.f};
    const f32x4 swd = {0.001f, 0.001f, 0.001f, 0.001f};

    // candidate cells for xy window +-3
    int cx0 = max(x - 3, 0) >> 3, cx1 = min(x + 3, 255) >> 3;
    int cy0 = max(y - 3, 0) >> 3, cy1 = min(y + 3, 255) >> 3;

    int tot = 0;
    for (int cx = cx0; cx <= cx1; ++cx)
        for (int cy = cy0; cy <= cy1; ++cy)
            tot += counts[(cx << 5) | cy];

    if (tot == 0) {                               // pure stream: nt stores
        __builtin_nontemporal_store(zq,  &sem4[smbase + lane]);
        __builtin_nontemporal_store(zq,  &sem4[smbase + 64 + lane]);
        __builtin_nontemporal_store(zq,  &sem4[smbase + 128 + lane]);
        __builtin_nontemporal_store(swd, &wsum4[wsbase + lane]);
        return;
    }

    // ---- defaults issued FIRST (plain: L2-combined with the sparse rewrite) ----
    sem4[smbase + lane]       = zq;
    sem4[smbase + 64 + lane]  = zq;
    sem4[smbase + 128 + lane] = zq;
    wsum4[wsbase + lane]      = swd;

    float acc[4][4];
#pragma unroll
    for (int q = 0; q < 4; ++q) {
        acc[q][0] = 0.f; acc[q][1] = 0.f; acc[q][2] = 0.f; acc[q][3] = 0.f;
    }

    const float inv = 1.0f / 256.0f;
    float fx  = ((float)x  + 0.5f) * inv - 0.5f;
    float fy  = ((float)y  + 0.5f) * inv - 0.5f;
    float fz0 = ((float)z0 + 0.5f) * inv - 0.5f;

    int lin0 = (col << 8) + z0;
    const f32x4 o4 = __builtin_nontemporal_load((const f32x4*)&occ[lin0]);
    float occv[4] = {o4.x, o4.y, o4.z, o4.w};

    for (int cx = cx0; cx <= cx1; ++cx)
    for (int cy = cy0; cy <= cy1; ++cy) {
        int cell = (cx << 5) | cy;
        int cn = min(counts[cell], XCAP);
        int base = cell * XCAP * 2;
        for (int j = 0; j < cn; ++j) {
            f32x4 r0 = lists[base + 2 * j];       // wave-uniform address
            int pk = __float_as_int(r0.w);
            int cxb = (pk >> 20) & 1023;          // cx + 8
            int cyb = (pk >> 10) & 1023;
            int czb =  pk        & 1023;
            // wave-uniform xy window test -> scalar branch
            if ((unsigned)(x + 11 - cxb) > 6u || (unsigned)(y + 11 - cyb) > 6u)
                continue;
            f32x4 r1 = lists[base + 2 * j + 1];
            float dx = fx - r0.x, dy = fy - r0.y;
            float exy = __expf(-8192.0f * (dx * dx + dy * dy));
            // per-lane z-quad overlap: z0 - cz + 6 in [0,9]
            if ((unsigned)(z0 + 14 - czb) <= 9u) {
#pragma unroll
                for (int q = 0; q < 4; ++q) {
                    unsigned dzi = (unsigned)(z0 + q + 11 - czb);  // z - cz + 3
                    if (dzi > 6u) continue;
                    if (occv[q] <= 0.0f) continue;
                    float dz = fz0 + (float)q * inv - r0.z;
                    float w = exy * __expf(-8192.0f * dz * dz);
                    acc[q][0] += w * r1.x;
                    acc[q][1] += w * r1.y;
                    acc[q][2] += w * r1.z;
                    acc[q][3] += w;
                }
            }
        }
    }

    float aw = acc[0][3] + acc[1][3] + acc[2][3] + acc[3][3];
    if (aw > 0.0f) {                              // touched lane: 64B rewrite
        int t = lin0 >> 2;                        // col*64 + lane
        f32x4 s0 = {acc[0][0], acc[0][1], acc[0][2], acc[1][0]};
        f32x4 s1 = {acc[1][1], acc[1][2], acc[2][0], acc[2][1]};
        f32x4 s2 = {acc[2][2], acc[3][0], acc[3][1], acc[3][2]};
        f32x4 sw = {0.001f + acc[0][3], 0.001f + acc[1][3],
                    0.001f + acc[2][3], 0.001f + acc[3][3]};
        sem4[t * 3 + 0] = s0;
        sem4[t * 3 + 1] = s1;
        sem4[t * 3 + 2] = s2;
        wsum4[t] = sw;
    }
}

extern "C" void kernel_launch(void* const* d_in, const int* in_sizes, int n_in,
                              void* d_out, int out_size, void* d_ws, size_t ws_size,
                              hipStream_t stream) {
    const float* verts = (const float*)d_in[0];   // (6890,3) f32
    const float* codes = (const float*)d_in[1];   // (6890,3) f32
    const float* occ   = (const float*)d_in[2];   // (256,256,256) f32
    // d_in[3] = smpl_faces (unused by the reference computation)

    f32x4* sem4  = (f32x4*)d_out;                       // 12,582,912 f32x4
    f32x4* wsum4 = (f32x4*)((float*)d_out + SEM_ELEMS); // 4,194,304 f32x4

    int*   counts = (int*)d_ws;                   // 4 KB
    f32x4* lists  = (f32x4*)(counts + 1024);      // 1024*64*2 f32x4 = 2 MB

    svox_zero<<<4, 256, 0, stream>>>(counts);
    svox_bucket_xy<<<(NV + 255) / 256, 256, 0, stream>>>(verts, codes, counts, lists);
    svox_gather<<<(RES * RES) / 4, 256, 0, stream>>>(occ, counts, lists, sem4, wsum4);
}